// Round 14
// baseline (288.666 us; speedup 1.0000x reference)
//
#include <hip/hip_runtime.h>

#define D 128
#define XSH 136   // f16 row stride for out_mfma staging

#define SHIFT 11
#define NPB   2048            // nodes per bucket = 1 << SHIFT
#define EPT   8               // edges per thread in csr pass 1

typedef _Float16 f16;
typedef __attribute__((ext_vector_type(4))) _Float16 f16x4;
typedef __attribute__((ext_vector_type(8))) _Float16 f16x8;
typedef __attribute__((ext_vector_type(4))) float    f32x4;

__device__ __forceinline__ float silu_f(float x) {
    return x / (1.0f + __expf(-x));
}

// ---------------- weight pre-convert ----------------
// Square mats: FRAG-MAJOR, 16384 f16 each: offset (nt*4+kk)*512 + l*8 + j holds
// W[k][n] with n = nt*16 + (l&15), k = kk*32 + (l>>4)*8 + j.
// Wo stays [n][k] (K=384) for out_mfma.
struct WPtrs { const float* s0; const float* s1; const float* s2;
               const float* s3; const float* s4; const float* s5; };
__global__ void wconv_all_kernel(WPtrs wp, const float* __restrict__ Wo, f16* __restrict__ WT)
{
    const int blk = blockIdx.x, t = threadIdx.x;
    if (blk < 384) {
        const int wid = blk >> 6;
        const int o = ((blk & 63) << 8) + t;       // 0..16383
        const int fi = o >> 9, r = o & 511;
        const int l = r >> 3, j = r & 7;
        const int nt = fi >> 2, kk = fi & 3;
        const int n = nt * 16 + (l & 15);
        const int k = kk * 32 + ((l >> 4) << 3) + j;
        const float* s;
        switch (wid) {
            case 0: s = wp.s0; break;
            case 1: s = wp.s1; break;
            case 2: s = wp.s2; break;
            case 3: s = wp.s3; break;
            case 4: s = wp.s4; break;
            default: s = wp.s5; break;
        }
        WT[(wid << 14) + o] = (f16)s[(k << 7) + n];
    } else {
        const int off = ((blk - 384) << 8) + t;    // 0..49151 = n*384+k
        const int n = off / 384, k = off - n * 384;
        WT[(6 << 14) + off] = (f16)Wo[k * 128 + n];
    }
}

// ---------------- MLP via MFMA: 16-wave blocks, wave-independent ----------------
// Block = 1024 thr = 16 waves; LDS = 64KB weights (Wa|Wb frag-major) + 16x4KB y-scratch
// = 128KB -> 1 block/CU = 16 waves/CU (2x the 4-wave variant's TLP).
// Each wave owns a 16-row tile end-to-end; cross-tile register prefetch depth 1;
// y/z through wave-private XOR-swizzled LDS, lgkmcnt-only ordering; no loop barriers.
// Swapped mfma(W,x): lane(cl,kg) -> out[row=cl][col=nt*16+kg*4+reg].
template<bool GATHER>
__launch_bounds__(1024, 4)
__global__ void mlp_mfma_kernel(const void* __restrict__ in_, const int* __restrict__ src,
                                const f16* __restrict__ Wfm,
                                const float* __restrict__ ba, const float* __restrict__ bb,
                                f16* __restrict__ out, int nrows)
{
    __shared__ f16 wlds[32768];    // Wa(16384) | Wb(16384), frag-major (64KB)
    __shared__ f16 ys[16][2048];   // per-wave 16x128 f16, XOR-swizzled (64KB)
    const int t = threadIdx.x;
    const int w = t >> 6, l = t & 63;
    const int cl = l & 15, kg = l >> 4;

    // ---- cooperative weight load: 64KB linear copy (once per block) ----
    #pragma unroll
    for (int i = 0; i < 4; ++i) {
        const int o = (t + i * 1024) * 8;
        *(f16x8*)(wlds + o) = *(const f16x8*)(Wfm + o);
    }
    __syncthreads();   // only barrier: weights ready

    f16* ysw = ys[w];
    auto ysoff = [&](int row, int b) -> int {
        return row * 128 + ((b ^ (((row & 3) << 6) | (((row >> 2) & 3) << 4))) >> 1);
    };

    const int ntile = (nrows + 15) >> 4;
    const int stride = (int)gridDim.x * 16;
    int tile = blockIdx.x * 16 + w;
    if (tile >= ntile) return;

    // prefetch staging registers
    f16x8 pa[4], pb[4];    // GATHER path (raw rows; product at use)
    float4 pf[8];          // fp32 path

    auto ISSUE = [&](int tl) {
        const int g = tl * 16 + cl;
        if (g >= nrows) return;
        if (GATHER) {
            const f16* in = (const f16*)in_;
            const int a = src[2 * g], b = src[2 * g + 1];
            #pragma unroll
            for (int kk = 0; kk < 4; ++kk) {
                pa[kk] = *(const f16x8*)(in + (size_t)a * D + kk * 32 + kg * 8);
                pb[kk] = *(const f16x8*)(in + (size_t)b * D + kk * 32 + kg * 8);
            }
        } else {
            const float* in = (const float*)in_;
            #pragma unroll
            for (int kk = 0; kk < 4; ++kk) {
                pf[2 * kk]     = *(const float4*)(in + (size_t)g * D + kk * 32 + kg * 8);
                pf[2 * kk + 1] = *(const float4*)(in + (size_t)g * D + kk * 32 + kg * 8 + 4);
            }
        }
    };

    ISSUE(tile);   // prologue

    while (true) {
        const int nxt = tile + stride;
        const int g = tile * 16 + cl;

        // ---- consume staged regs -> xf (vmcnt wait lands here, a full tile late) ----
        f16x8 xf[4];
        if (g < nrows) {
            if (GATHER) {
                #pragma unroll
                for (int kk = 0; kk < 4; ++kk) {
                    f16x8 hv;
                    #pragma unroll
                    for (int j = 0; j < 8; ++j) hv[j] = (f16)((float)pa[kk][j] * (float)pb[kk][j]);
                    xf[kk] = hv;
                }
            } else {
                #pragma unroll
                for (int kk = 0; kk < 4; ++kk) {
                    const float4 v0 = pf[2 * kk], v1 = pf[2 * kk + 1];
                    f16x8 hv = {(f16)v0.x, (f16)v0.y, (f16)v0.z, (f16)v0.w,
                                (f16)v1.x, (f16)v1.y, (f16)v1.z, (f16)v1.w};
                    xf[kk] = hv;
                }
            }
        } else {
            f16x8 z = {};
            #pragma unroll
            for (int kk = 0; kk < 4; ++kk) xf[kk] = z;
        }

        // ---- issue next tile's gathers; they fly under this tile's compute ----
        if (nxt < ntile) ISSUE(nxt);

        f32x4 acc[8];

        // ---- stage B: y = silu(x @ Wa + ba) ----
        #pragma unroll
        for (int nt = 0; nt < 8; ++nt) acc[nt] = (f32x4){0.f, 0.f, 0.f, 0.f};
        #pragma unroll
        for (int kk = 0; kk < 4; ++kk)
            #pragma unroll
            for (int nt = 0; nt < 8; ++nt) {
                const f16x8 wf = *(const f16x8*)(wlds + ((nt * 4 + kk) * 64 + l) * 8);
                acc[nt] = __builtin_amdgcn_mfma_f32_16x16x32_f16(wf, xf[kk], acc[nt], 0, 0, 0);
            }
        #pragma unroll
        for (int nt = 0; nt < 8; ++nt) {
            const float4 bv = *(const float4*)&ba[nt * 16 + kg * 4];
            f16x4 y;
            y[0] = (f16)silu_f(acc[nt][0] + bv.x);
            y[1] = (f16)silu_f(acc[nt][1] + bv.y);
            y[2] = (f16)silu_f(acc[nt][2] + bv.z);
            y[3] = (f16)silu_f(acc[nt][3] + bv.w);
            *(f16x4*)(ysw + ysoff(cl, nt * 32 + kg * 8)) = y;
        }
        asm volatile("s_waitcnt lgkmcnt(0)" ::: "memory");
        __builtin_amdgcn_sched_barrier(0);

        // ---- reload y as B-operand frags (wave-private, no barrier) ----
        #pragma unroll
        for (int kk = 0; kk < 4; ++kk)
            xf[kk] = *(const f16x8*)(ysw + ysoff(cl, kk * 64 + kg * 16));

        // ---- stage C: z = y @ Wb + bb ----
        #pragma unroll
        for (int nt = 0; nt < 8; ++nt) acc[nt] = (f32x4){0.f, 0.f, 0.f, 0.f};
        #pragma unroll
        for (int kk = 0; kk < 4; ++kk)
            #pragma unroll
            for (int nt = 0; nt < 8; ++nt) {
                const f16x8 wf = *(const f16x8*)(wlds + (16384 + ((nt * 4 + kk) * 64 + l) * 8));
                acc[nt] = __builtin_amdgcn_mfma_f32_16x16x32_f16(wf, xf[kk], acc[nt], 0, 0, 0);
            }
        #pragma unroll
        for (int nt = 0; nt < 8; ++nt) {
            const float4 bv = *(const float4*)&bb[nt * 16 + kg * 4];
            f16x4 z;
            z[0] = (f16)(acc[nt][0] + bv.x);
            z[1] = (f16)(acc[nt][1] + bv.y);
            z[2] = (f16)(acc[nt][2] + bv.z);
            z[3] = (f16)(acc[nt][3] + bv.w);
            *(f16x4*)(ysw + ysoff(cl, nt * 32 + kg * 8)) = z;
        }
        asm volatile("s_waitcnt lgkmcnt(0)" ::: "memory");
        __builtin_amdgcn_sched_barrier(0);

        // ---- coalesced 16B stores (4KB tile, linear across lanes) ----
        #pragma unroll
        for (int i = 0; i < 4; ++i) {
            const int lin = i * 1024 + l * 16;          // byte offset within tile
            const int row = lin >> 8, b = lin & 255;
            const int gr = tile * 16 + row;
            if (gr < nrows) {
                const f16x8 v = *(const f16x8*)(ysw + ysoff(row, b));
                *(f16x8*)(out + (size_t)gr * D + (b >> 1)) = v;
            }
        }

        if (nxt >= ntile) break;
        tile = nxt;
    }
}

// ------------ final (FUSED): out = silu(concat(h1, Σh2t, Σh2dn) @ Wo + bo) ----------
// Parts 1/2 are gather-sums over CSR12 (payload = n2 row), computed during staging.
__launch_bounds__(256)
__global__ void out_mfma_kernel(const f16* __restrict__ h1, const f16* __restrict__ h2t,
                                const f16* __restrict__ h2dn,
                                const int2* __restrict__ offcnt, const int* __restrict__ el,
                                const f16* __restrict__ WoT, const float* __restrict__ bo,
                                float* __restrict__ out, int nrows)
{
    __shared__ f16 xs[64][XSH];
    const int t = threadIdx.x;
    const int w = t >> 6, l = t & 63;
    const int cl = l & 15, kg = l >> 4;
    const int r = t >> 2, q = t & 3;
    const int row0 = blockIdx.x * 64;
    const int g = row0 + r;

    f32x4 acc[2][4];
    #pragma unroll
    for (int nt = 0; nt < 2; ++nt)
        #pragma unroll
        for (int m = 0; m < 4; ++m) acc[nt][m] = (f32x4){0.f, 0.f, 0.f, 0.f};

    #pragma unroll
    for (int p = 0; p < 3; ++p) {
        if (p) __syncthreads();
        {   // ---- stage part p: thread (r,q) fills 32 cols of row r ----
            f16* dst = &xs[r][q * 32];
            if (g >= nrows) {
                f16x8 z = {};
                #pragma unroll
                for (int i = 0; i < 4; ++i) *(f16x8*)(dst + 8 * i) = z;
            } else if (p == 0) {
                const f16x8* pp = (const f16x8*)(h1 + (size_t)g * D + q * 32);
                #pragma unroll
                for (int i = 0; i < 4; ++i) *(f16x8*)(dst + 8 * i) = pp[i];
            } else {
                const f16* srcbuf = (p == 1) ? h2t : h2dn;
                float fa[32];
                #pragma unroll
                for (int i = 0; i < 32; ++i) fa[i] = 0.f;
                const int2 oc = offcnt[g];
                const int base = oc.x, deg = oc.y;
                int d = 0;
                for (; d + 2 <= deg; d += 2) {
                    const int j0 = el[base + d], j1 = el[base + d + 1];
                    const f16x8* p0 = (const f16x8*)(srcbuf + (size_t)j0 * D + q * 32);
                    const f16x8* p1 = (const f16x8*)(srcbuf + (size_t)j1 * D + q * 32);
                    #pragma unroll
                    for (int i = 0; i < 4; ++i) {
                        const f16x8 v0 = p0[i], v1 = p1[i];
                        #pragma unroll
                        for (int j = 0; j < 8; ++j)
                            fa[i * 8 + j] += (float)v0[j] + (float)v1[j];
                    }
                }
                if (d < deg) {
                    const int j0 = el[base + d];
                    const f16x8* p0 = (const f16x8*)(srcbuf + (size_t)j0 * D + q * 32);
                    #pragma unroll
                    for (int i = 0; i < 4; ++i) {
                        const f16x8 v0 = p0[i];
                        #pragma unroll
                        for (int j = 0; j < 8; ++j) fa[i * 8 + j] += (float)v0[j];
                    }
                }
                #pragma unroll
                for (int i = 0; i < 4; ++i) {
                    f16x8 hv;
                    #pragma unroll
                    for (int j = 0; j < 8; ++j) hv[j] = (f16)fa[i * 8 + j];
                    *(f16x8*)(dst + 8 * i) = hv;
                }
            }
        }
        __syncthreads();
        f16x8 wo[2][4];
        #pragma unroll
        for (int nt = 0; nt < 2; ++nt)
            #pragma unroll
            for (int kk = 0; kk < 4; ++kk)
                wo[nt][kk] = *(const f16x8*)(WoT + (size_t)((w * 2 + nt) * 16 + cl) * 384
                                             + p * D + kk * 32 + kg * 8);
        #pragma unroll
        for (int m = 0; m < 4; ++m)
            #pragma unroll
            for (int kk = 0; kk < 4; ++kk) {
                const f16x8 a = *(const f16x8*)&xs[m * 16 + cl][kk * 32 + kg * 8];
                acc[0][m] = __builtin_amdgcn_mfma_f32_16x16x32_f16(wo[0][kk], a, acc[0][m], 0, 0, 0);
                acc[1][m] = __builtin_amdgcn_mfma_f32_16x16x32_f16(wo[1][kk], a, acc[1][m], 0, 0, 0);
            }
    }

    // direct float4 stores: row = row0+m*16+cl, n0 = w*32+nt*16+kg*4
    #pragma unroll
    for (int nt = 0; nt < 2; ++nt) {
        const int n0 = w * 32 + nt * 16 + kg * 4;
        const float4 bv = *(const float4*)&bo[n0];
        #pragma unroll
        for (int m = 0; m < 4; ++m) {
            const int gr = row0 + m * 16 + cl;
            if (gr < nrows) {
                float4 v = make_float4(silu_f(acc[nt][m][0] + bv.x),
                                       silu_f(acc[nt][m][1] + bv.y),
                                       silu_f(acc[nt][m][2] + bv.z),
                                       silu_f(acc[nt][m][3] + bv.w));
                *(float4*)(out + (size_t)gr * D + n0) = v;
            }
        }
    }
}

// ================= bucketed reverse-CSR build =================
__global__ void bucket_hist_kernel(const int* __restrict__ s12, int E12,
                                   const int* __restrict__ s23, int E23,
                                   const int* __restrict__ s34, int E34,
                                   int* __restrict__ bcnt, int N1, int N2, int nbkt)
{
    __shared__ int h[256];
    const int t = threadIdx.x;
    for (int i = t; i < 256; i += blockDim.x) h[i] = 0;
    __syncthreads();
    const int Etot = E12 + E23 + E34;
    for (int g = blockIdx.x * blockDim.x + t; g < Etot; g += gridDim.x * blockDim.x) {
        int node;
        if (g < E12) node = s12[g];
        else if (g < E12 + E23) node = N1 + s23[g - E12];
        else node = N1 + N2 + s34[g - E12 - E23];
        atomicAdd(&h[node >> SHIFT], 1);
    }
    __syncthreads();
    for (int i = t; i < nbkt; i += blockDim.x)
        if (h[i]) atomicAdd(&bcnt[i], h[i]);
}

__global__ void bucket_scan_kernel(const int* __restrict__ bcnt, int* __restrict__ bbase,
                                   int* __restrict__ bcur, int nbkt, int Etot)
{
    __shared__ int s[256];
    const int t = threadIdx.x;
    const int v = (t < nbkt) ? bcnt[t] : 0;
    s[t] = v;
    __syncthreads();
    for (int d = 1; d < 256; d <<= 1) {
        const int u = (t >= d) ? s[t - d] : 0;
        __syncthreads();
        s[t] += u;
        __syncthreads();
    }
    if (t < nbkt) { const int ex = s[t] - v; bbase[t] = ex; bcur[t] = ex; }
    if (t == 0) bbase[nbkt] = Etot;
}

__global__ void csr_pass1_kernel(const int* __restrict__ s12, int E12,
                                 const int* __restrict__ s23, int E23,
                                 const int* __restrict__ s34, int E34,
                                 int* __restrict__ bcur, int2* __restrict__ recs,
                                 int N1, int N2, int nbkt)
{
    __shared__ int cnt[256];
    __shared__ int gbase[256];
    const int t = threadIdx.x;
    const int chunk = blockIdx.x * (256 * EPT);
    const int Etot = E12 + E23 + E34;
    for (int i = t; i < 256; i += 256) cnt[i] = 0;
    __syncthreads();
    int node_[EPT], pay_[EPT], br_[EPT];
    #pragma unroll
    for (int i = 0; i < EPT; ++i) {
        const int g = chunk + i * 256 + t;
        int node = -1, pay = 0, b = 0, r = 0;
        if (g < Etot) {
            if (g < E12) { node = s12[g]; pay = g >> 1; }
            else if (g < E12 + E23) { const int e = g - E12; node = N1 + s23[e]; pay = e >> 1; }
            else { const int e = g - E12 - E23; node = N1 + N2 + s34[e]; pay = s34[e ^ 1]; }
            b = node >> SHIFT;
            r = atomicAdd(&cnt[b], 1);
        }
        node_[i] = node; pay_[i] = pay; br_[i] = (b << 16) | r;
    }
    __syncthreads();
    if (t < nbkt && cnt[t]) gbase[t] = atomicAdd(&bcur[t], cnt[t]);
    __syncthreads();
    #pragma unroll
    for (int i = 0; i < EPT; ++i) {
        if (node_[i] >= 0) {
            const int b = br_[i] >> 16, r = br_[i] & 0xffff;
            recs[gbase[b] + r] = make_int2(node_[i], pay_[i]);
        }
    }
}

__launch_bounds__(1024)
__global__ void csr_pass2_kernel(const int2* __restrict__ recs,
                                 const int* __restrict__ bbase,
                                 int2* __restrict__ offcnt, int* __restrict__ el, int NT)
{
    __shared__ int cnt2[NPB];
    __shared__ int pref[NPB];
    __shared__ int s1[NPB / 2];
    const int b = blockIdx.x, t = threadIdx.x;     // blockDim = 1024 = NPB/2
    const int node0 = b << SHIFT;
    const int k0 = bbase[b], k1 = bbase[b + 1];
    for (int i = t; i < NPB; i += 1024) cnt2[i] = 0;
    __syncthreads();
    for (int k = k0 + t; k < k1; k += 1024)
        atomicAdd(&cnt2[recs[k].x - node0], 1);
    __syncthreads();
    s1[t] = cnt2[2 * t] + cnt2[2 * t + 1];
    __syncthreads();
    for (int d = 1; d < 1024; d <<= 1) {
        const int u = (t >= d) ? s1[t - d] : 0;
        __syncthreads();
        s1[t] += u;
        __syncthreads();
    }
    {
        const int a = cnt2[2 * t];
        const int pairsum = a + cnt2[2 * t + 1];
        const int ex0 = s1[t] - pairsum;
        pref[2 * t] = ex0;
        pref[2 * t + 1] = ex0 + a;
    }
    __syncthreads();
    for (int i = t; i < NPB; i += 1024) {
        const int node = node0 + i;
        if (node < NT) offcnt[node] = make_int2(k0 + pref[i], cnt2[i]);
    }
    __syncthreads();
    for (int k = k0 + t; k < k1; k += 1024) {
        const int2 r = recs[k];
        const int pos = atomicAdd(&pref[r.x - node0], 1);
        el[k0 + pos] = r.y;
    }
}

// ---- h3dn[i] = h3t[i] * sum of h3t[sibling] (payload = sibling index), f16 out ----
__global__ void prod_gather_kernel(const f16* __restrict__ h3t,
                                   const int2* __restrict__ offcnt,
                                   const int* __restrict__ el,
                                   f16* __restrict__ h3dn, int nrows)
{
    const long long g = (long long)blockIdx.x * blockDim.x + threadIdx.x;
    const int i = (int)(g >> 4);
    if (i >= nrows) return;
    const int c = ((int)g & 15) * 8;
    const f16x8 ownv = *(const f16x8*)(h3t + (size_t)i * D + c);
    float acc0[8] = {}, acc1[8] = {};
    const int2 oc = offcnt[i];
    const int base = oc.x, deg = oc.y;
    int d = 0;
    for (; d + 4 <= deg; d += 4) {
        const int s0 = el[base + d + 0], s1v = el[base + d + 1];
        const int s2 = el[base + d + 2], s3v = el[base + d + 3];
        const f16x8 v0 = *(const f16x8*)(h3t + (size_t)s0 * D + c);
        const f16x8 v1 = *(const f16x8*)(h3t + (size_t)s1v * D + c);
        const f16x8 v2 = *(const f16x8*)(h3t + (size_t)s2 * D + c);
        const f16x8 v3 = *(const f16x8*)(h3t + (size_t)s3v * D + c);
        #pragma unroll
        for (int j = 0; j < 8; ++j) {
            acc0[j] += (float)v0[j] + (float)v2[j];
            acc1[j] += (float)v1[j] + (float)v3[j];
        }
    }
    for (; d < deg; ++d) {
        const int s0 = el[base + d];
        const f16x8 v0 = *(const f16x8*)(h3t + (size_t)s0 * D + c);
        #pragma unroll
        for (int j = 0; j < 8; ++j) acc0[j] += (float)v0[j];
    }
    f16x8 r;
    #pragma unroll
    for (int j = 0; j < 8; ++j) r[j] = (f16)((acc0[j] + acc1[j]) * (float)ownv[j]);
    *(f16x8*)(h3dn + (size_t)i * D + c) = r;
}

// ---- dst[i] = sum of val[payload] over CSR entries (f16 in/out, fp32 accum) ----
__global__ void gather_sum_kernel(const f16* __restrict__ val,
                                  const int2* __restrict__ offcnt,
                                  const int* __restrict__ el,
                                  f16* __restrict__ dst, int nrows)
{
    const long long g = (long long)blockIdx.x * blockDim.x + threadIdx.x;
    const int i = (int)(g >> 4);
    if (i >= nrows) return;
    const int c = ((int)g & 15) * 8;
    float acc0[8] = {}, acc1[8] = {};
    const int2 oc = offcnt[i];
    const int base = oc.x, deg = oc.y;
    int d = 0;
    for (; d + 4 <= deg; d += 4) {
        const int s0 = el[base + d + 0], s1v = el[base + d + 1];
        const int s2 = el[base + d + 2], s3v = el[base + d + 3];
        const f16x8 v0 = *(const f16x8*)(val + (size_t)s0 * D + c);
        const f16x8 v1 = *(const f16x8*)(val + (size_t)s1v * D + c);
        const f16x8 v2 = *(const f16x8*)(val + (size_t)s2 * D + c);
        const f16x8 v3 = *(const f16x8*)(val + (size_t)s3v * D + c);
        #pragma unroll
        for (int j = 0; j < 8; ++j) {
            acc0[j] += (float)v0[j] + (float)v2[j];
            acc1[j] += (float)v1[j] + (float)v3[j];
        }
    }
    for (; d < deg; ++d) {
        const int s0 = el[base + d];
        const f16x8 v0 = *(const f16x8*)(val + (size_t)s0 * D + c);
        #pragma unroll
        for (int j = 0; j < 8; ++j) acc0[j] += (float)v0[j];
    }
    f16x8 r;
    #pragma unroll
    for (int j = 0; j < 8; ++j) r[j] = (f16)(acc0[j] + acc1[j]);
    *(f16x8*)(dst + (size_t)i * D + c) = r;
}

// diagnostic: if workspace too small, report its size via d_out[0]
__global__ void ws_report_kernel(float* out, float v) {
    if (threadIdx.x == 0 && blockIdx.x == 0) out[0] = v;
}

extern "C" void kernel_launch(void* const* d_in, const int* in_sizes, int n_in,
                              void* d_out, int out_size, void* d_ws, size_t ws_size,
                              hipStream_t stream)
{
    const float* feat = (const float*)d_in[0];
    const float* W1a = (const float*)d_in[1];  const float* b1a = (const float*)d_in[2];
    const float* W1b = (const float*)d_in[3];  const float* b1b = (const float*)d_in[4];
    const float* W2a = (const float*)d_in[5];  const float* b2a = (const float*)d_in[6];
    const float* W2b = (const float*)d_in[7];  const float* b2b = (const float*)d_in[8];
    const float* W3a = (const float*)d_in[9];  const float* b3a = (const float*)d_in[10];
    const float* W3b = (const float*)d_in[11]; const float* b3b = (const float*)d_in[12];
    const float* Wo  = (const float*)d_in[13]; const float* bo  = (const float*)d_in[14];
    const int* src12 = (const int*)d_in[15];
    const int* src23 = (const int*)d_in[17];
    const int* src34 = (const int*)d_in[19];

    const int N1 = in_sizes[0] / D;
    const int N2 = in_sizes[15] / 2;
    const int N3 = in_sizes[17] / 2;
    const int N4 = in_sizes[19] / 2;
    const int E12 = 2 * N2, E23 = 2 * N3, E34 = 2 * N4;
    const int NT = N1 + N2 + N3;
    const int Etot = E12 + E23 + E34;
    const int NBKT = (NT + NPB - 1) >> SHIFT;

    // ---- workspace layout ----
    char* p = (char*)d_ws;
    f16* h1    = (f16*)p;  p += (size_t)N1 * D * sizeof(f16);
    f16* h2t   = (f16*)p;  p += (size_t)N2 * D * sizeof(f16);
    f16* h3t   = (f16*)p;  f16* h2dn  = h3t;    // alias: h3t dead after prod_gather
    p += (size_t)N3 * D * sizeof(f16);
    f16* h3dn  = (f16*)p;                        // dead after h2dn gather
    p += (size_t)N3 * D * sizeof(f16);

    p = (char*)(((uintptr_t)p + 15) & ~(uintptr_t)15);
    int2* offcnt = (int2*)p;             p += (size_t)NT * sizeof(int2);
    int2* recs   = (int2*)p;             p += (size_t)Etot * sizeof(int2);
    int*  el     = (int*)p;              p += (size_t)Etot * sizeof(int);
    int*  bcnt   = (int*)p;              p += 256 * sizeof(int);
    int*  bbase  = (int*)p;              p += 257 * sizeof(int);
    int*  bcur   = (int*)p;              p += 256 * sizeof(int);

    p = (char*)(((uintptr_t)p + 31) & ~(uintptr_t)31);
    f16* WT = (f16*)p;                   // 6 frag-major square mats + WoT
    f16* Wp1 = WT;                       // W1a|W1b
    f16* Wp2 = WT + 2 * 16384;           // W2a|W2b
    f16* Wp3 = WT + 4 * 16384;           // W3a|W3b
    f16* WoT = WT + 6 * 16384;           // [128][384]
    p = (char*)(WoT + 384 * D);

    const size_t need = p - (char*)d_ws;
    if (ws_size < need || NBKT > 256) {
        ws_report_kernel<<<1, 64, 0, stream>>>((float*)d_out, (float)ws_size);
        return;
    }

    dim3 blk(256);
    auto rowblk16 = [](long long rows) { return dim3((unsigned)((rows * 16 + 255) / 256)); };
    auto mlpgrid  = [](int n) {
        const int nt16 = (((n + 15) >> 4) + 15) / 16;
        return dim3((unsigned)(nt16 < 256 ? nt16 : 256));
    };

    // ---- weight convert: one launch ----
    WPtrs wp = {W1a, W1b, W2a, W2b, W3a, W3b};
    wconv_all_kernel<<<dim3(576), blk, 0, stream>>>(wp, Wo, WT);

    // ---- bucketed CSR build ----
    hipMemsetAsync(bcnt, 0, 256 * sizeof(int), stream);
    {
        const int nblk = (Etot + 2047) / 2048;
        bucket_hist_kernel<<<dim3((unsigned)nblk), blk, 0, stream>>>(
            src12, E12, src23, E23, src34, E34, bcnt, N1, N2, NBKT);
        bucket_scan_kernel<<<1, 256, 0, stream>>>(bcnt, bbase, bcur, NBKT, Etot);
        csr_pass1_kernel<<<dim3((unsigned)((Etot + 256 * EPT - 1) / (256 * EPT))), blk, 0, stream>>>(
            src12, E12, src23, E23, src34, E34, bcur, recs, N1, N2, NBKT);
        csr_pass2_kernel<<<dim3((unsigned)NBKT), dim3(1024), 0, stream>>>(
            recs, bbase, offcnt, el, NT);
    }

    // ---- upward (16-wave barrier-free MFMA MLPs, f16 intermediates) ----
    mlp_mfma_kernel<false><<<mlpgrid(N1), dim3(1024), 0, stream>>>(feat, nullptr, Wp1, b1a, b1b, h1, N1);
    mlp_mfma_kernel<true ><<<mlpgrid(N2), dim3(1024), 0, stream>>>(h1, src12, Wp2, b2a, b2b, h2t, N2);
    mlp_mfma_kernel<true ><<<mlpgrid(N3), dim3(1024), 0, stream>>>(h2t, src23, Wp3, b3a, b3b, h3t, N3);

    // ---- downward (f16, fp32 accum; pre-resolved payloads) ----
    prod_gather_kernel<<<rowblk16(N3), blk, 0, stream>>>(h3t, offcnt + N1 + N2, el, h3dn, N3);
    gather_sum_kernel<<<rowblk16(N2), blk, 0, stream>>>(h3dn, offcnt + N1, el, h2dn, N2);

    // ---- final fused: concat-gathers (CSR12) + linear + SiLU (f32 out) ----
    out_mfma_kernel<<<dim3((unsigned)((N1 + 63) / 64)), blk, 0, stream>>>(
        h1, h2t, h2dn, offcnt, el, WoT, bo, (float*)d_out, N1);
}

// Round 15
// 248.171 us; speedup vs baseline: 1.1632x; 1.1632x over previous
//
#include <hip/hip_runtime.h>

#define D 128
#define XSH 136   // f16 row stride for out_mfma staging

#define SHIFT 11
#define NPB   2048            // nodes per bucket = 1 << SHIFT
#define EPT   8               // edges per thread in csr pass 1

typedef _Float16 f16;
typedef __attribute__((ext_vector_type(4))) _Float16 f16x4;
typedef __attribute__((ext_vector_type(8))) _Float16 f16x8;
typedef __attribute__((ext_vector_type(4))) float    f32x4;

__device__ __forceinline__ float silu_f(float x) {
    return x / (1.0f + __expf(-x));
}

// ---------------- weight pre-convert ----------------
// Square mats: FRAG-MAJOR, 16384 f16 each: offset (nt*4+kk)*512 + l*8 + j holds
// W[k][n] with n = nt*16 + (l&15), k = kk*32 + (l>>4)*8 + j.
// Wo stays [n][k] (K=384) for out_mfma.
struct WPtrs { const float* s0; const float* s1; const float* s2;
               const float* s3; const float* s4; const float* s5; };
__global__ void wconv_all_kernel(WPtrs wp, const float* __restrict__ Wo, f16* __restrict__ WT)
{
    const int blk = blockIdx.x, t = threadIdx.x;
    if (blk < 384) {
        const int wid = blk >> 6;
        const int o = ((blk & 63) << 8) + t;       // 0..16383
        const int fi = o >> 9, r = o & 511;
        const int l = r >> 3, j = r & 7;
        const int nt = fi >> 2, kk = fi & 3;
        const int n = nt * 16 + (l & 15);
        const int k = kk * 32 + ((l >> 4) << 3) + j;
        const float* s;
        switch (wid) {
            case 0: s = wp.s0; break;
            case 1: s = wp.s1; break;
            case 2: s = wp.s2; break;
            case 3: s = wp.s3; break;
            case 4: s = wp.s4; break;
            default: s = wp.s5; break;
        }
        WT[(wid << 14) + o] = (f16)s[(k << 7) + n];
    } else {
        const int off = ((blk - 384) << 8) + t;    // 0..49151 = n*384+k
        const int n = off / 384, k = off - n * 384;
        WT[(6 << 14) + off] = (f16)Wo[k * 128 + n];
    }
}

// ---------------- MLP via MFMA: r11 configuration (proven best) ----------------
// Block = 256 thr = 4 waves; LDS = 64KB weights (Wa|Wb frag-major, linear-copied)
// + 4x4KB per-wave XOR-swizzled y-scratch = 80KB -> 2 blocks/CU.
// Each wave owns a 16-row tile end-to-end; cross-tile register prefetch depth 1;
// y/z via wave-private LDS with lgkmcnt-only ordering; no loop barriers; no VGPR cap.
// Swapped mfma(W,x): lane(cl,kg) -> out[row=cl][col=nt*16+kg*4+reg].
template<bool GATHER>
__launch_bounds__(256)
__global__ void mlp_mfma_kernel(const void* __restrict__ in_, const int* __restrict__ src,
                                const f16* __restrict__ Wfm,
                                const float* __restrict__ ba, const float* __restrict__ bb,
                                f16* __restrict__ out, int nrows)
{
    __shared__ f16 wlds[32768];   // Wa(16384) | Wb(16384), frag-major (64KB)
    __shared__ f16 ys[4][2048];   // per-wave 16x128 f16, XOR-swizzled (16KB)
    const int t = threadIdx.x;
    const int w = t >> 6, l = t & 63;
    const int cl = l & 15, kg = l >> 4;

    // ---- cooperative weight load: 64KB linear copy (once per block) ----
    #pragma unroll
    for (int i = 0; i < 16; ++i) {
        const int o = (t + i * 256) * 8;
        *(f16x8*)(wlds + o) = *(const f16x8*)(Wfm + o);
    }
    __syncthreads();   // only barrier: weights ready

    f16* ysw = ys[w];
    auto ysoff = [&](int row, int b) -> int {
        return row * 128 + ((b ^ (((row & 3) << 6) | (((row >> 2) & 3) << 4))) >> 1);
    };

    const int ntile = (nrows + 15) >> 4;
    const int stride = (int)gridDim.x * 4;
    int tile = blockIdx.x * 4 + w;
    if (tile >= ntile) return;

    // prefetch staging registers
    f16x8 pa[4], pb[4];    // GATHER path (raw rows; product at use)
    float4 pf[8];          // fp32 path

    auto ISSUE = [&](int tl) {
        const int g = tl * 16 + cl;
        if (g >= nrows) return;
        if (GATHER) {
            const f16* in = (const f16*)in_;
            const int a = src[2 * g], b = src[2 * g + 1];
            #pragma unroll
            for (int kk = 0; kk < 4; ++kk) {
                pa[kk] = *(const f16x8*)(in + (size_t)a * D + kk * 32 + kg * 8);
                pb[kk] = *(const f16x8*)(in + (size_t)b * D + kk * 32 + kg * 8);
            }
        } else {
            const float* in = (const float*)in_;
            #pragma unroll
            for (int kk = 0; kk < 4; ++kk) {
                pf[2 * kk]     = *(const float4*)(in + (size_t)g * D + kk * 32 + kg * 8);
                pf[2 * kk + 1] = *(const float4*)(in + (size_t)g * D + kk * 32 + kg * 8 + 4);
            }
        }
    };

    ISSUE(tile);   // prologue

    while (true) {
        const int nxt = tile + stride;
        const int g = tile * 16 + cl;

        // ---- consume staged regs -> xf (vmcnt wait lands here, a full tile late) ----
        f16x8 xf[4];
        if (g < nrows) {
            if (GATHER) {
                #pragma unroll
                for (int kk = 0; kk < 4; ++kk) {
                    f16x8 hv;
                    #pragma unroll
                    for (int j = 0; j < 8; ++j) hv[j] = (f16)((float)pa[kk][j] * (float)pb[kk][j]);
                    xf[kk] = hv;
                }
            } else {
                #pragma unroll
                for (int kk = 0; kk < 4; ++kk) {
                    const float4 v0 = pf[2 * kk], v1 = pf[2 * kk + 1];
                    f16x8 hv = {(f16)v0.x, (f16)v0.y, (f16)v0.z, (f16)v0.w,
                                (f16)v1.x, (f16)v1.y, (f16)v1.z, (f16)v1.w};
                    xf[kk] = hv;
                }
            }
        } else {
            f16x8 z = {};
            #pragma unroll
            for (int kk = 0; kk < 4; ++kk) xf[kk] = z;
        }

        // ---- issue next tile's gathers; they fly under this tile's compute ----
        if (nxt < ntile) ISSUE(nxt);

        f32x4 acc[8];

        // ---- stage B: y = silu(x @ Wa + ba) ----
        #pragma unroll
        for (int nt = 0; nt < 8; ++nt) acc[nt] = (f32x4){0.f, 0.f, 0.f, 0.f};
        #pragma unroll
        for (int kk = 0; kk < 4; ++kk)
            #pragma unroll
            for (int nt = 0; nt < 8; ++nt) {
                const f16x8 wf = *(const f16x8*)(wlds + ((nt * 4 + kk) * 64 + l) * 8);
                acc[nt] = __builtin_amdgcn_mfma_f32_16x16x32_f16(wf, xf[kk], acc[nt], 0, 0, 0);
            }
        #pragma unroll
        for (int nt = 0; nt < 8; ++nt) {
            const float4 bv = *(const float4*)&ba[nt * 16 + kg * 4];
            f16x4 y;
            y[0] = (f16)silu_f(acc[nt][0] + bv.x);
            y[1] = (f16)silu_f(acc[nt][1] + bv.y);
            y[2] = (f16)silu_f(acc[nt][2] + bv.z);
            y[3] = (f16)silu_f(acc[nt][3] + bv.w);
            *(f16x4*)(ysw + ysoff(cl, nt * 32 + kg * 8)) = y;
        }
        asm volatile("s_waitcnt lgkmcnt(0)" ::: "memory");
        __builtin_amdgcn_sched_barrier(0);

        // ---- reload y as B-operand frags (wave-private, no barrier) ----
        #pragma unroll
        for (int kk = 0; kk < 4; ++kk)
            xf[kk] = *(const f16x8*)(ysw + ysoff(cl, kk * 64 + kg * 16));

        // ---- stage C: z = y @ Wb + bb ----
        #pragma unroll
        for (int nt = 0; nt < 8; ++nt) acc[nt] = (f32x4){0.f, 0.f, 0.f, 0.f};
        #pragma unroll
        for (int kk = 0; kk < 4; ++kk)
            #pragma unroll
            for (int nt = 0; nt < 8; ++nt) {
                const f16x8 wf = *(const f16x8*)(wlds + (16384 + ((nt * 4 + kk) * 64 + l) * 8));
                acc[nt] = __builtin_amdgcn_mfma_f32_16x16x32_f16(wf, xf[kk], acc[nt], 0, 0, 0);
            }
        #pragma unroll
        for (int nt = 0; nt < 8; ++nt) {
            const float4 bv = *(const float4*)&bb[nt * 16 + kg * 4];
            f16x4 z;
            z[0] = (f16)(acc[nt][0] + bv.x);
            z[1] = (f16)(acc[nt][1] + bv.y);
            z[2] = (f16)(acc[nt][2] + bv.z);
            z[3] = (f16)(acc[nt][3] + bv.w);
            *(f16x4*)(ysw + ysoff(cl, nt * 32 + kg * 8)) = z;
        }
        asm volatile("s_waitcnt lgkmcnt(0)" ::: "memory");
        __builtin_amdgcn_sched_barrier(0);

        // ---- coalesced 16B stores (4KB tile, linear across lanes) ----
        #pragma unroll
        for (int i = 0; i < 4; ++i) {
            const int lin = i * 1024 + l * 16;          // byte offset within tile
            const int row = lin >> 8, b = lin & 255;
            const int gr = tile * 16 + row;
            if (gr < nrows) {
                const f16x8 v = *(const f16x8*)(ysw + ysoff(row, b));
                *(f16x8*)(out + (size_t)gr * D + (b >> 1)) = v;
            }
        }

        if (nxt >= ntile) break;
        tile = nxt;
    }
}

// ------------ final (FUSED): out = silu(concat(h1, Σh2t, Σh2dn) @ Wo + bo) ----------
// Parts 1/2 are gather-sums over CSR12 (payload = n2 row), computed during staging.
__launch_bounds__(256)
__global__ void out_mfma_kernel(const f16* __restrict__ h1, const f16* __restrict__ h2t,
                                const f16* __restrict__ h2dn,
                                const int2* __restrict__ offcnt, const int* __restrict__ el,
                                const f16* __restrict__ WoT, const float* __restrict__ bo,
                                float* __restrict__ out, int nrows)
{
    __shared__ f16 xs[64][XSH];
    const int t = threadIdx.x;
    const int w = t >> 6, l = t & 63;
    const int cl = l & 15, kg = l >> 4;
    const int r = t >> 2, q = t & 3;
    const int row0 = blockIdx.x * 64;
    const int g = row0 + r;

    f32x4 acc[2][4];
    #pragma unroll
    for (int nt = 0; nt < 2; ++nt)
        #pragma unroll
        for (int m = 0; m < 4; ++m) acc[nt][m] = (f32x4){0.f, 0.f, 0.f, 0.f};

    #pragma unroll
    for (int p = 0; p < 3; ++p) {
        if (p) __syncthreads();
        {   // ---- stage part p: thread (r,q) fills 32 cols of row r ----
            f16* dst = &xs[r][q * 32];
            if (g >= nrows) {
                f16x8 z = {};
                #pragma unroll
                for (int i = 0; i < 4; ++i) *(f16x8*)(dst + 8 * i) = z;
            } else if (p == 0) {
                const f16x8* pp = (const f16x8*)(h1 + (size_t)g * D + q * 32);
                #pragma unroll
                for (int i = 0; i < 4; ++i) *(f16x8*)(dst + 8 * i) = pp[i];
            } else {
                const f16* srcbuf = (p == 1) ? h2t : h2dn;
                float fa[32];
                #pragma unroll
                for (int i = 0; i < 32; ++i) fa[i] = 0.f;
                const int2 oc = offcnt[g];
                const int base = oc.x, deg = oc.y;
                int d = 0;
                for (; d + 2 <= deg; d += 2) {
                    const int j0 = el[base + d], j1 = el[base + d + 1];
                    const f16x8* p0 = (const f16x8*)(srcbuf + (size_t)j0 * D + q * 32);
                    const f16x8* p1 = (const f16x8*)(srcbuf + (size_t)j1 * D + q * 32);
                    #pragma unroll
                    for (int i = 0; i < 4; ++i) {
                        const f16x8 v0 = p0[i], v1 = p1[i];
                        #pragma unroll
                        for (int j = 0; j < 8; ++j)
                            fa[i * 8 + j] += (float)v0[j] + (float)v1[j];
                    }
                }
                if (d < deg) {
                    const int j0 = el[base + d];
                    const f16x8* p0 = (const f16x8*)(srcbuf + (size_t)j0 * D + q * 32);
                    #pragma unroll
                    for (int i = 0; i < 4; ++i) {
                        const f16x8 v0 = p0[i];
                        #pragma unroll
                        for (int j = 0; j < 8; ++j) fa[i * 8 + j] += (float)v0[j];
                    }
                }
                #pragma unroll
                for (int i = 0; i < 4; ++i) {
                    f16x8 hv;
                    #pragma unroll
                    for (int j = 0; j < 8; ++j) hv[j] = (f16)fa[i * 8 + j];
                    *(f16x8*)(dst + 8 * i) = hv;
                }
            }
        }
        __syncthreads();
        f16x8 wo[2][4];
        #pragma unroll
        for (int nt = 0; nt < 2; ++nt)
            #pragma unroll
            for (int kk = 0; kk < 4; ++kk)
                wo[nt][kk] = *(const f16x8*)(WoT + (size_t)((w * 2 + nt) * 16 + cl) * 384
                                             + p * D + kk * 32 + kg * 8);
        #pragma unroll
        for (int m = 0; m < 4; ++m)
            #pragma unroll
            for (int kk = 0; kk < 4; ++kk) {
                const f16x8 a = *(const f16x8*)&xs[m * 16 + cl][kk * 32 + kg * 8];
                acc[0][m] = __builtin_amdgcn_mfma_f32_16x16x32_f16(wo[0][kk], a, acc[0][m], 0, 0, 0);
                acc[1][m] = __builtin_amdgcn_mfma_f32_16x16x32_f16(wo[1][kk], a, acc[1][m], 0, 0, 0);
            }
    }

    // direct float4 stores: row = row0+m*16+cl, n0 = w*32+nt*16+kg*4
    #pragma unroll
    for (int nt = 0; nt < 2; ++nt) {
        const int n0 = w * 32 + nt * 16 + kg * 4;
        const float4 bv = *(const float4*)&bo[n0];
        #pragma unroll
        for (int m = 0; m < 4; ++m) {
            const int gr = row0 + m * 16 + cl;
            if (gr < nrows) {
                float4 v = make_float4(silu_f(acc[nt][m][0] + bv.x),
                                       silu_f(acc[nt][m][1] + bv.y),
                                       silu_f(acc[nt][m][2] + bv.z),
                                       silu_f(acc[nt][m][3] + bv.w));
                *(float4*)(out + (size_t)gr * D + n0) = v;
            }
        }
    }
}

// ================= bucketed reverse-CSR build =================
__global__ void bucket_hist_kernel(const int* __restrict__ s12, int E12,
                                   const int* __restrict__ s23, int E23,
                                   const int* __restrict__ s34, int E34,
                                   int* __restrict__ bcnt, int N1, int N2, int nbkt)
{
    __shared__ int h[256];
    const int t = threadIdx.x;
    for (int i = t; i < 256; i += blockDim.x) h[i] = 0;
    __syncthreads();
    const int Etot = E12 + E23 + E34;
    for (int g = blockIdx.x * blockDim.x + t; g < Etot; g += gridDim.x * blockDim.x) {
        int node;
        if (g < E12) node = s12[g];
        else if (g < E12 + E23) node = N1 + s23[g - E12];
        else node = N1 + N2 + s34[g - E12 - E23];
        atomicAdd(&h[node >> SHIFT], 1);
    }
    __syncthreads();
    for (int i = t; i < nbkt; i += blockDim.x)
        if (h[i]) atomicAdd(&bcnt[i], h[i]);
}

__global__ void bucket_scan_kernel(const int* __restrict__ bcnt, int* __restrict__ bbase,
                                   int* __restrict__ bcur, int nbkt, int Etot)
{
    __shared__ int s[256];
    const int t = threadIdx.x;
    const int v = (t < nbkt) ? bcnt[t] : 0;
    s[t] = v;
    __syncthreads();
    for (int d = 1; d < 256; d <<= 1) {
        const int u = (t >= d) ? s[t - d] : 0;
        __syncthreads();
        s[t] += u;
        __syncthreads();
    }
    if (t < nbkt) { const int ex = s[t] - v; bbase[t] = ex; bcur[t] = ex; }
    if (t == 0) bbase[nbkt] = Etot;
}

__global__ void csr_pass1_kernel(const int* __restrict__ s12, int E12,
                                 const int* __restrict__ s23, int E23,
                                 const int* __restrict__ s34, int E34,
                                 int* __restrict__ bcur, int2* __restrict__ recs,
                                 int N1, int N2, int nbkt)
{
    __shared__ int cnt[256];
    __shared__ int gbase[256];
    const int t = threadIdx.x;
    const int chunk = blockIdx.x * (256 * EPT);
    const int Etot = E12 + E23 + E34;
    for (int i = t; i < 256; i += 256) cnt[i] = 0;
    __syncthreads();
    int node_[EPT], pay_[EPT], br_[EPT];
    #pragma unroll
    for (int i = 0; i < EPT; ++i) {
        const int g = chunk + i * 256 + t;
        int node = -1, pay = 0, b = 0, r = 0;
        if (g < Etot) {
            if (g < E12) { node = s12[g]; pay = g >> 1; }
            else if (g < E12 + E23) { const int e = g - E12; node = N1 + s23[e]; pay = e >> 1; }
            else { const int e = g - E12 - E23; node = N1 + N2 + s34[e]; pay = s34[e ^ 1]; }
            b = node >> SHIFT;
            r = atomicAdd(&cnt[b], 1);
        }
        node_[i] = node; pay_[i] = pay; br_[i] = (b << 16) | r;
    }
    __syncthreads();
    if (t < nbkt && cnt[t]) gbase[t] = atomicAdd(&bcur[t], cnt[t]);
    __syncthreads();
    #pragma unroll
    for (int i = 0; i < EPT; ++i) {
        if (node_[i] >= 0) {
            const int b = br_[i] >> 16, r = br_[i] & 0xffff;
            recs[gbase[b] + r] = make_int2(node_[i], pay_[i]);
        }
    }
}

__launch_bounds__(1024)
__global__ void csr_pass2_kernel(const int2* __restrict__ recs,
                                 const int* __restrict__ bbase,
                                 int2* __restrict__ offcnt, int* __restrict__ el, int NT)
{
    __shared__ int cnt2[NPB];
    __shared__ int pref[NPB];
    __shared__ int s1[NPB / 2];
    const int b = blockIdx.x, t = threadIdx.x;     // blockDim = 1024 = NPB/2
    const int node0 = b << SHIFT;
    const int k0 = bbase[b], k1 = bbase[b + 1];
    for (int i = t; i < NPB; i += 1024) cnt2[i] = 0;
    __syncthreads();
    for (int k = k0 + t; k < k1; k += 1024)
        atomicAdd(&cnt2[recs[k].x - node0], 1);
    __syncthreads();
    s1[t] = cnt2[2 * t] + cnt2[2 * t + 1];
    __syncthreads();
    for (int d = 1; d < 1024; d <<= 1) {
        const int u = (t >= d) ? s1[t - d] : 0;
        __syncthreads();
        s1[t] += u;
        __syncthreads();
    }
    {
        const int a = cnt2[2 * t];
        const int pairsum = a + cnt2[2 * t + 1];
        const int ex0 = s1[t] - pairsum;
        pref[2 * t] = ex0;
        pref[2 * t + 1] = ex0 + a;
    }
    __syncthreads();
    for (int i = t; i < NPB; i += 1024) {
        const int node = node0 + i;
        if (node < NT) offcnt[node] = make_int2(k0 + pref[i], cnt2[i]);
    }
    __syncthreads();
    for (int k = k0 + t; k < k1; k += 1024) {
        const int2 r = recs[k];
        const int pos = atomicAdd(&pref[r.x - node0], 1);
        el[k0 + pos] = r.y;
    }
}

// ---- h3dn[i] = h3t[i] * sum of h3t[sibling] (payload = sibling index), f16 out ----
__global__ void prod_gather_kernel(const f16* __restrict__ h3t,
                                   const int2* __restrict__ offcnt,
                                   const int* __restrict__ el,
                                   f16* __restrict__ h3dn, int nrows)
{
    const long long g = (long long)blockIdx.x * blockDim.x + threadIdx.x;
    const int i = (int)(g >> 4);
    if (i >= nrows) return;
    const int c = ((int)g & 15) * 8;
    const f16x8 ownv = *(const f16x8*)(h3t + (size_t)i * D + c);
    float acc0[8] = {}, acc1[8] = {};
    const int2 oc = offcnt[i];
    const int base = oc.x, deg = oc.y;
    int d = 0;
    for (; d + 4 <= deg; d += 4) {
        const int s0 = el[base + d + 0], s1v = el[base + d + 1];
        const int s2 = el[base + d + 2], s3v = el[base + d + 3];
        const f16x8 v0 = *(const f16x8*)(h3t + (size_t)s0 * D + c);
        const f16x8 v1 = *(const f16x8*)(h3t + (size_t)s1v * D + c);
        const f16x8 v2 = *(const f16x8*)(h3t + (size_t)s2 * D + c);
        const f16x8 v3 = *(const f16x8*)(h3t + (size_t)s3v * D + c);
        #pragma unroll
        for (int j = 0; j < 8; ++j) {
            acc0[j] += (float)v0[j] + (float)v2[j];
            acc1[j] += (float)v1[j] + (float)v3[j];
        }
    }
    for (; d < deg; ++d) {
        const int s0 = el[base + d];
        const f16x8 v0 = *(const f16x8*)(h3t + (size_t)s0 * D + c);
        #pragma unroll
        for (int j = 0; j < 8; ++j) acc0[j] += (float)v0[j];
    }
    f16x8 r;
    #pragma unroll
    for (int j = 0; j < 8; ++j) r[j] = (f16)((acc0[j] + acc1[j]) * (float)ownv[j]);
    *(f16x8*)(h3dn + (size_t)i * D + c) = r;
}

// ---- dst[i] = sum of val[payload] over CSR entries (f16 in/out, fp32 accum) ----
__global__ void gather_sum_kernel(const f16* __restrict__ val,
                                  const int2* __restrict__ offcnt,
                                  const int* __restrict__ el,
                                  f16* __restrict__ dst, int nrows)
{
    const long long g = (long long)blockIdx.x * blockDim.x + threadIdx.x;
    const int i = (int)(g >> 4);
    if (i >= nrows) return;
    const int c = ((int)g & 15) * 8;
    float acc0[8] = {}, acc1[8] = {};
    const int2 oc = offcnt[i];
    const int base = oc.x, deg = oc.y;
    int d = 0;
    for (; d + 4 <= deg; d += 4) {
        const int s0 = el[base + d + 0], s1v = el[base + d + 1];
        const int s2 = el[base + d + 2], s3v = el[base + d + 3];
        const f16x8 v0 = *(const f16x8*)(val + (size_t)s0 * D + c);
        const f16x8 v1 = *(const f16x8*)(val + (size_t)s1v * D + c);
        const f16x8 v2 = *(const f16x8*)(val + (size_t)s2 * D + c);
        const f16x8 v3 = *(const f16x8*)(val + (size_t)s3v * D + c);
        #pragma unroll
        for (int j = 0; j < 8; ++j) {
            acc0[j] += (float)v0[j] + (float)v2[j];
            acc1[j] += (float)v1[j] + (float)v3[j];
        }
    }
    for (; d < deg; ++d) {
        const int s0 = el[base + d];
        const f16x8 v0 = *(const f16x8*)(val + (size_t)s0 * D + c);
        #pragma unroll
        for (int j = 0; j < 8; ++j) acc0[j] += (float)v0[j];
    }
    f16x8 r;
    #pragma unroll
    for (int j = 0; j < 8; ++j) r[j] = (f16)(acc0[j] + acc1[j]);
    *(f16x8*)(dst + (size_t)i * D + c) = r;
}

// diagnostic: if workspace too small, report its size via d_out[0]
__global__ void ws_report_kernel(float* out, float v) {
    if (threadIdx.x == 0 && blockIdx.x == 0) out[0] = v;
}

extern "C" void kernel_launch(void* const* d_in, const int* in_sizes, int n_in,
                              void* d_out, int out_size, void* d_ws, size_t ws_size,
                              hipStream_t stream)
{
    const float* feat = (const float*)d_in[0];
    const float* W1a = (const float*)d_in[1];  const float* b1a = (const float*)d_in[2];
    const float* W1b = (const float*)d_in[3];  const float* b1b = (const float*)d_in[4];
    const float* W2a = (const float*)d_in[5];  const float* b2a = (const float*)d_in[6];
    const float* W2b = (const float*)d_in[7];  const float* b2b = (const float*)d_in[8];
    const float* W3a = (const float*)d_in[9];  const float* b3a = (const float*)d_in[10];
    const float* W3b = (const float*)d_in[11]; const float* b3b = (const float*)d_in[12];
    const float* Wo  = (const float*)d_in[13]; const float* bo  = (const float*)d_in[14];
    const int* src12 = (const int*)d_in[15];
    const int* src23 = (const int*)d_in[17];
    const int* src34 = (const int*)d_in[19];

    const int N1 = in_sizes[0] / D;
    const int N2 = in_sizes[15] / 2;
    const int N3 = in_sizes[17] / 2;
    const int N4 = in_sizes[19] / 2;
    const int E12 = 2 * N2, E23 = 2 * N3, E34 = 2 * N4;
    const int NT = N1 + N2 + N3;
    const int Etot = E12 + E23 + E34;
    const int NBKT = (NT + NPB - 1) >> SHIFT;

    // ---- workspace layout ----
    char* p = (char*)d_ws;
    f16* h1    = (f16*)p;  p += (size_t)N1 * D * sizeof(f16);
    f16* h2t   = (f16*)p;  p += (size_t)N2 * D * sizeof(f16);
    f16* h3t   = (f16*)p;  f16* h2dn  = h3t;    // alias: h3t dead after prod_gather
    p += (size_t)N3 * D * sizeof(f16);
    f16* h3dn  = (f16*)p;                        // dead after h2dn gather
    p += (size_t)N3 * D * sizeof(f16);

    p = (char*)(((uintptr_t)p + 15) & ~(uintptr_t)15);
    int2* offcnt = (int2*)p;             p += (size_t)NT * sizeof(int2);
    int2* recs   = (int2*)p;             p += (size_t)Etot * sizeof(int2);
    int*  el     = (int*)p;              p += (size_t)Etot * sizeof(int);
    int*  bcnt   = (int*)p;              p += 256 * sizeof(int);
    int*  bbase  = (int*)p;              p += 257 * sizeof(int);
    int*  bcur   = (int*)p;              p += 256 * sizeof(int);

    p = (char*)(((uintptr_t)p + 31) & ~(uintptr_t)31);
    f16* WT = (f16*)p;                   // 6 frag-major square mats + WoT
    f16* Wp1 = WT;                       // W1a|W1b
    f16* Wp2 = WT + 2 * 16384;           // W2a|W2b
    f16* Wp3 = WT + 4 * 16384;           // W3a|W3b
    f16* WoT = WT + 6 * 16384;           // [128][384]
    p = (char*)(WoT + 384 * D);

    const size_t need = p - (char*)d_ws;
    if (ws_size < need || NBKT > 256) {
        ws_report_kernel<<<1, 64, 0, stream>>>((float*)d_out, (float)ws_size);
        return;
    }

    dim3 blk(256);
    auto rowblk16 = [](long long rows) { return dim3((unsigned)((rows * 16 + 255) / 256)); };
    auto mlpgrid  = [](int n) {
        const int nt4 = (((n + 15) >> 4) + 3) / 4;
        return dim3((unsigned)(nt4 < 512 ? nt4 : 512));
    };

    // ---- weight convert: one launch ----
    WPtrs wp = {W1a, W1b, W2a, W2b, W3a, W3b};
    wconv_all_kernel<<<dim3(576), blk, 0, stream>>>(wp, Wo, WT);

    // ---- bucketed CSR build ----
    hipMemsetAsync(bcnt, 0, 256 * sizeof(int), stream);
    {
        const int nblk = (Etot + 2047) / 2048;
        bucket_hist_kernel<<<dim3((unsigned)nblk), blk, 0, stream>>>(
            src12, E12, src23, E23, src34, E34, bcnt, N1, N2, NBKT);
        bucket_scan_kernel<<<1, 256, 0, stream>>>(bcnt, bbase, bcur, NBKT, Etot);
        csr_pass1_kernel<<<dim3((unsigned)((Etot + 256 * EPT - 1) / (256 * EPT))), blk, 0, stream>>>(
            src12, E12, src23, E23, src34, E34, bcur, recs, N1, N2, NBKT);
        csr_pass2_kernel<<<dim3((unsigned)NBKT), dim3(1024), 0, stream>>>(
            recs, bbase, offcnt, el, NT);
    }

    // ---- upward (r11-config barrier-free MFMA MLPs, f16 intermediates) ----
    mlp_mfma_kernel<false><<<mlpgrid(N1), blk, 0, stream>>>(feat, nullptr, Wp1, b1a, b1b, h1, N1);
    mlp_mfma_kernel<true ><<<mlpgrid(N2), blk, 0, stream>>>(h1, src12, Wp2, b2a, b2b, h2t, N2);
    mlp_mfma_kernel<true ><<<mlpgrid(N3), blk, 0, stream>>>(h2t, src23, Wp3, b3a, b3b, h3t, N3);

    // ---- downward (f16, fp32 accum; pre-resolved payloads) ----
    prod_gather_kernel<<<rowblk16(N3), blk, 0, stream>>>(h3t, offcnt + N1 + N2, el, h3dn, N3);
    gather_sum_kernel<<<rowblk16(N2), blk, 0, stream>>>(h3dn, offcnt + N1, el, h2dn, N2);

    // ---- final fused: concat-gathers (CSR12) + linear + SiLU (f32 out) ----
    out_mfma_kernel<<<dim3((unsigned)((N1 + 63) / 64)), blk, 0, stream>>>(
        h1, h2t, h2dn, offcnt, el, WoT, bo, (float*)d_out, N1);
}